// Round 1
// baseline (115.917 us; speedup 1.0000x reference)
//
#include <hip/hip_runtime.h>
#include <hip/hip_bf16.h>

#define NN 8192
#define DD 128

typedef short bf16x8v __attribute__((ext_vector_type(8)));
typedef float f32x4  __attribute__((ext_vector_type(4)));

constexpr float SCALE2  = 14.426950408889634f; // (1/T) * log2(e) = 10*log2(e)
constexpr float LN2     = 0.6931471805599453f;
constexpr float NEG_BIG = -1.0e30f;
constexpr float M_INIT  = -3.0e38f;

// ---------------- kernel 1: fp32 -> bf16 (RNE) ----------------
__global__ __launch_bounds__(256) void k_convert(const float* __restrict__ z,
                                                 unsigned short* __restrict__ zb) {
  int i = blockIdx.x * blockDim.x + threadIdx.x; // one float4 per thread
  const float4 v = reinterpret_cast<const float4*>(z)[i];
  auto cvt = [](float f) -> unsigned short {
    unsigned u = __float_as_uint(f);
    unsigned r = (u + 0x7fffu + ((u >> 16) & 1u)) >> 16;
    return (unsigned short)r;
  };
  ushort4 o;
  o.x = cvt(v.x); o.y = cvt(v.y); o.z = cvt(v.z); o.w = cvt(v.w);
  reinterpret_cast<ushort4*>(zb)[i] = o;
}

// ---------------- kernel 2: fused Gram + online reductions ----------------
// Swapped MFMA orientation: A = "j" rows of z, B = anchor rows of z.
// Output tile: col (lane&15) = anchor, row (lane>>4)*4+reg = j offset.
// Each lane owns 2 anchors (t=0,1) and sees 16 j's per 64-col iteration.
__global__ __launch_bounds__(256) void k_main(const unsigned short* __restrict__ zb,
                                              const int* __restrict__ labels,
                                              float4* __restrict__ partials,
                                              int colsPerChunk, int NC) {
  const int lane = threadIdx.x & 63;
  const int wid  = threadIdx.x >> 6;
  const int lr   = lane & 15;   // anchor offset within tile
  const int lg   = lane >> 4;   // k-group / j-subgroup
  const int rowbase = blockIdx.x * 128 + wid * 32;
  const int cb      = blockIdx.y;
  const int cStart  = cb * colsPerChunk;
  const int cEnd    = cStart + colsPerChunk;

  // Hoisted B fragments (anchor rows), labels, indices
  bf16x8v bfr[2][4];
  int i_[2]; int labi[2];
#pragma unroll
  for (int t = 0; t < 2; ++t) {
    int row = rowbase + t * 16 + lr;
    i_[t]   = row;
    labi[t] = labels[row];
#pragma unroll
    for (int ks = 0; ks < 4; ++ks)
      bfr[t][ks] = *reinterpret_cast<const bf16x8v*>(zb + (size_t)row * DD + ks * 32 + lg * 8);
  }

  float m[2]   = {M_INIT, M_INIT};
  float s[2]   = {0.f, 0.f};
  float con[2] = {0.f, 0.f};
  float cnt[2] = {0.f, 0.f};

  for (int c0 = cStart; c0 < cEnd; c0 += 64) {
    // A fragments: 4 column-subtiles x 4 K-steps
    bf16x8v afr[4][4];
    int4 labj[4];
#pragma unroll
    for (int st = 0; st < 4; ++st) {
#pragma unroll
      for (int ks = 0; ks < 4; ++ks)
        afr[st][ks] = *reinterpret_cast<const bf16x8v*>(
            zb + (size_t)(c0 + st * 16 + lr) * DD + ks * 32 + lg * 8);
      labj[st] = *reinterpret_cast<const int4*>(labels + c0 + st * 16 + lg * 4);
    }

    f32x4 acc[2][4];
#pragma unroll
    for (int t = 0; t < 2; ++t) {
#pragma unroll
      for (int st = 0; st < 4; ++st) {
        acc[t][st] = (f32x4){0.f, 0.f, 0.f, 0.f};
#pragma unroll
        for (int ks = 0; ks < 4; ++ks)
          acc[t][st] = __builtin_amdgcn_mfma_f32_16x16x32_bf16(afr[st][ks], bfr[t][ks],
                                                               acc[t][st], 0, 0, 0);
      }
    }

#pragma unroll
    for (int t = 0; t < 2; ++t) {
      float xl[16];
      float tm = M_INIT;
#pragma unroll
      for (int st = 0; st < 4; ++st) {
#pragma unroll
        for (int r = 0; r < 4; ++r) {
          float x2 = acc[t][st][r] * SCALE2;              // log2-domain scaled sim
          int j  = c0 + st * 16 + lg * 4 + r;
          int lj = (r == 0) ? labj[st].x : (r == 1) ? labj[st].y
                 : (r == 2) ? labj[st].z : labj[st].w;
          bool mt = (lj == labi[t]);
          bool dg = (j == i_[t]);
          float v = mt ? (x2 - 1.0f) : x2;                // + log2(0.5) = -1
          v = dg ? NEG_BIG : v;                           // exclude diagonal
          xl[st * 4 + r] = v;
          float wm = (mt && !dg) ? 1.0f : 0.0f;
          con[t] = fmaf(x2, wm, con[t]);
          cnt[t] += wm;
          tm = fmaxf(tm, v);
        }
      }
      float mn = fmaxf(m[t], tm);
      float ssum = 0.f;
#pragma unroll
      for (int k = 0; k < 16; ++k) ssum += exp2f(xl[k] - mn);
      s[t] = fmaf(s[t], exp2f(m[t] - mn), ssum);
      m[t] = mn;
    }
  }

  // Merge partial state across the 4 lane-groups (xor 16, 32)
#pragma unroll
  for (int off = 16; off <= 32; off <<= 1) {
#pragma unroll
    for (int t = 0; t < 2; ++t) {
      float mo = __shfl_xor(m[t], off);
      float so = __shfl_xor(s[t], off);
      float co = __shfl_xor(con[t], off);
      float no = __shfl_xor(cnt[t], off);
      float mn = fmaxf(m[t], mo);
      s[t] = s[t] * exp2f(m[t] - mn) + so * exp2f(mo - mn);
      m[t] = mn;
      con[t] += co;
      cnt[t] += no;
    }
  }

  if (lg == 0) {
#pragma unroll
    for (int t = 0; t < 2; ++t)
      partials[(size_t)i_[t] * NC + cb] = make_float4(m[t], s[t], con[t], cnt[t]);
  }
}

// ---------------- kernel 3: deterministic final merge ----------------
__global__ __launch_bounds__(1024) void k_final(const float4* __restrict__ partials,
                                                float* __restrict__ out, int NC) {
  int tid = threadIdx.x;
  float local = 0.f;
  for (int r = tid; r < NN; r += 1024) {
    float m = M_INIT, s = 0.f, con = 0.f, cnt = 0.f;
    for (int c = 0; c < NC; ++c) {
      float4 p = partials[(size_t)r * NC + c];
      float mn = fmaxf(m, p.x);
      s = s * exp2f(m - mn) + p.y * exp2f(p.x - mn);
      m = mn; con += p.z; cnt += p.w;
    }
    if (cnt > 0.5f) local += LN2 * (m + log2f(s) - con / cnt);
  }
  __shared__ float red[16];
  int lane = tid & 63, w = tid >> 6;
#pragma unroll
  for (int off = 32; off >= 1; off >>= 1) local += __shfl_xor(local, off);
  if (lane == 0) red[w] = local;
  __syncthreads();
  if (tid == 0) {
    float tot = 0.f;
#pragma unroll
    for (int i = 0; i < 16; ++i) tot += red[i];
    out[0] = tot / (float)NN;
  }
}

extern "C" void kernel_launch(void* const* d_in, const int* in_sizes, int n_in,
                              void* d_out, int out_size, void* d_ws, size_t ws_size,
                              hipStream_t stream) {
  const float* z      = (const float*)d_in[0];
  const int*   labels = (const int*)d_in[1];

  unsigned short* zb = (unsigned short*)d_ws;
  float4* partials   = (float4*)((char*)d_ws + (size_t)NN * DD * 2);

  int NC = 8;
  while (NC > 1 && (size_t)NN * DD * 2 + (size_t)NN * NC * sizeof(float4) > ws_size) NC >>= 1;
  int colsPerChunk = NN / NC;

  hipLaunchKernelGGL(k_convert, dim3(NN * DD / 4 / 256), dim3(256), 0, stream, z, zb);
  hipLaunchKernelGGL(k_main, dim3(NN / 128, NC), dim3(256), 0, stream,
                     zb, labels, partials, colsPerChunk, NC);
  hipLaunchKernelGGL(k_final, dim3(1), dim3(1024), 0, stream, partials, (float*)d_out, NC);
}